// Round 2
// baseline (11702.096 us; speedup 1.0000x reference)
//
#include <hip/hip_runtime.h>
#include <hip/hip_bf16.h>

// ---------------------------------------------------------------------------
// UniMol encoder forward, fp32 correctness-first baseline (round 2).
//   B=8 L=256 D=512 H=64 DH=8 NL=15 K=128 V=128 F=2048, PAD token = 0.
// Changes vs round 1:
//  * attn softmax + PV fused -> attnP buffer deleted (ws 311 MB -> 176 MB,
//    and -268 MB HBM traffic per layer).
//  * ws_size guard: insufficient ws now fails with poisoned output instead of
//    a GPU page-fault core dump (diagnosable).
// ---------------------------------------------------------------------------

#define Bb 8
#define Ll 256
#define Dd 512
#define Hh 64
#define DHh 8
#define NLl 15
#define Kk 128
#define Ff 2048

__device__ inline float gelu_f(float v) {
    return 0.5f * v * (1.0f + erff(v * 0.70710678118654752f));
}

__device__ inline float block_sum256(float v, float* sbuf) {
#pragma unroll
    for (int o2 = 32; o2; o2 >>= 1) v += __shfl_down(v, o2);
    __syncthreads();                      // protect sbuf reuse across calls
    if ((threadIdx.x & 63) == 0) sbuf[threadIdx.x >> 6] = v;
    __syncthreads();
    return sbuf[0] + sbuf[1] + sbuf[2] + sbuf[3];
}

// ---------------------------------------------------------------------------
// Fused GaussianLayer + NonLinearHead (K->K gelu K->H) + transpose + pad mask.
// Block: 256 threads handles (b, i, 32 j's). Output bias[b,h,i,j].
// ---------------------------------------------------------------------------
#define JT 32
__global__ __launch_bounds__(256) void gbf_head_kernel(
    const float* __restrict__ dist, const int* __restrict__ etype,
    const int* __restrict__ tokens,
    const float* __restrict__ means, const float* __restrict__ stds,
    const float* __restrict__ gmul, const float* __restrict__ gbias,
    const float* __restrict__ w1, const float* __restrict__ b1,
    const float* __restrict__ w2, const float* __restrict__ b2,
    float* __restrict__ bias_out)
{
    const int tid = threadIdx.x;
    const int j0 = blockIdx.x * JT;
    const int i  = blockIdx.y;
    const int b  = blockIdx.z;

    __shared__ float mean_s[Kk], istd_s[Kk], coef_s[Kk], b1_s[Kk];
    __shared__ float b2_s[Hh];
    __shared__ float y_s[JT];
    __shared__ int   padj_s[JT];
    __shared__ float gbf_s[JT][Kk];      // 16 KB
    __shared__ float u_s[JT][Kk + 1];    // 16.5 KB, +1 pad for bank spread

    const float SQRT_2PI_F = sqrtf(2.0f * 3.14159f);  // matches python literal
    if (tid < Kk) {
        float sd = fabsf(stds[tid]) + 1e-5f;
        float is = 1.0f / sd;
        mean_s[tid] = means[tid];
        istd_s[tid] = is;
        coef_s[tid] = is / SQRT_2PI_F;
        b1_s[tid]   = b1[tid];
    }
    if (tid < Hh) b2_s[tid] = b2[tid];
    if (tid < JT) {
        int j = j0 + tid;
        int t = etype[((size_t)b * Ll + i) * Ll + j];
        y_s[tid]    = gmul[t] * dist[((size_t)b * Ll + i) * Ll + j] + gbias[t];
        padj_s[tid] = (tokens[b * Ll + j] == 0);
    }
    __syncthreads();

    // phase 0: gaussian basis, JT x K
    for (int idx = tid; idx < JT * Kk; idx += 256) {
        int jl = idx >> 7, kk = idx & 127;
        float a = (y_s[jl] - mean_s[kk]) * istd_s[kk];
        gbf_s[jl][kk] = coef_s[kk] * expf(-0.5f * a * a);
    }
    __syncthreads();

    // phase 1: u = gelu(gbf @ w1 + b1), JT x K outputs
    {
        const int kp4 = 4 * (tid & 31);       // output column base (0..124)
        const int jb  = (tid >> 5) * 4;       // jl base (0..28)
        float acc[4][4] = {};
        for (int kk = 0; kk < Kk; ++kk) {
            float4 w = *(const float4*)&w1[kk * Kk + kp4];
            float g[4];
#pragma unroll
            for (int r = 0; r < 4; ++r) g[r] = gbf_s[jb + r][kk];
#pragma unroll
            for (int r = 0; r < 4; ++r) {
                acc[r][0] += g[r] * w.x; acc[r][1] += g[r] * w.y;
                acc[r][2] += g[r] * w.z; acc[r][3] += g[r] * w.w;
            }
        }
#pragma unroll
        for (int r = 0; r < 4; ++r)
#pragma unroll
            for (int c = 0; c < 4; ++c)
                u_s[jb + r][kp4 + c] = gelu_f(acc[r][c] + b1_s[kp4 + c]);
    }
    __syncthreads();

    // phase 2: hb = u @ w2 + b2, JT x H outputs. Stage into hb_s (alias gbf_s).
    float (*hb_s)[Hh + 1] = reinterpret_cast<float (*)[Hh + 1]>(&gbf_s[0][0]);
    {
        const int h4  = 4 * (tid >> 4);       // h base (0..60)
        const int jb2 = 2 * (tid & 15);       // jl base (0..30)
        float acc[2][4] = {};
        for (int kk = 0; kk < Kk; ++kk) {
            float4 w = *(const float4*)&w2[kk * Hh + h4];
            float u0 = u_s[jb2 + 0][kk];
            float u1 = u_s[jb2 + 1][kk];
            acc[0][0] += u0 * w.x; acc[0][1] += u0 * w.y; acc[0][2] += u0 * w.z; acc[0][3] += u0 * w.w;
            acc[1][0] += u1 * w.x; acc[1][1] += u1 * w.y; acc[1][2] += u1 * w.z; acc[1][3] += u1 * w.w;
        }
        __syncthreads();   // gbf_s reads done everywhere before aliasing write
#pragma unroll
        for (int r = 0; r < 2; ++r)
#pragma unroll
            for (int c = 0; c < 4; ++c)
                hb_s[jb2 + r][h4 + c] = acc[r][c] + b2_s[h4 + c];
    }
    __syncthreads();

    // phase 3: write bias[b,h,i,j] with -inf at padded key columns, j coalesced
    for (int idx = tid; idx < Hh * JT; idx += 256) {
        int hh = idx >> 5, jl = idx & 31;
        float v = padj_s[jl] ? -INFINITY : hb_s[jl][hh];
        bias_out[(((size_t)b * Hh + hh) * Ll + i) * Ll + j0 + jl] = v;
    }
}

// ---------------------------------------------------------------------------
// Token embedding gather + LayerNorm + pad-row zeroing. One block per row.
// ---------------------------------------------------------------------------
__global__ __launch_bounds__(256) void embed_ln_kernel(
    const int* __restrict__ tokens, const float* __restrict__ emb,
    const float* __restrict__ g, const float* __restrict__ bt,
    float* __restrict__ x)
{
    int row = blockIdx.x;
    int tid = threadIdx.x;
    int tok = tokens[row];
    const float* e = emb + (size_t)tok * Dd;
    float v0 = e[tid], v1 = e[tid + 256];
    __shared__ float sbuf[4];
    float mean = block_sum256(v0 + v1, sbuf) * (1.0f / Dd);
    float d0 = v0 - mean, d1 = v1 - mean;
    float var = block_sum256(d0 * d0 + d1 * d1, sbuf) * (1.0f / Dd);
    float inv = 1.0f / sqrtf(var + 1e-5f);
    float mask = (tok == 0) ? 0.0f : 1.0f;
    x[(size_t)row * Dd + tid]       = (d0 * inv * g[tid] + bt[tid]) * mask;
    x[(size_t)row * Dd + tid + 256] = (d1 * inv * g[tid + 256] + bt[tid + 256]) * mask;
}

// ---------------------------------------------------------------------------
// Generic LayerNorm (optionally masked by pad rows). One block per row.
// ---------------------------------------------------------------------------
__global__ __launch_bounds__(256) void ln_kernel(
    const float* __restrict__ xin, const float* __restrict__ g,
    const float* __restrict__ bt, const int* __restrict__ tokens,
    float* __restrict__ y)
{
    int row = blockIdx.x;
    int tid = threadIdx.x;
    const float* xr = xin + (size_t)row * Dd;
    float v0 = xr[tid], v1 = xr[tid + 256];
    __shared__ float sbuf[4];
    float mean = block_sum256(v0 + v1, sbuf) * (1.0f / Dd);
    float d0 = v0 - mean, d1 = v1 - mean;
    float var = block_sum256(d0 * d0 + d1 * d1, sbuf) * (1.0f / Dd);
    float inv = 1.0f / sqrtf(var + 1e-5f);
    float mask = 1.0f;
    if (tokens) mask = (tokens[row] == 0) ? 0.0f : 1.0f;
    y[(size_t)row * Dd + tid]       = (d0 * inv * g[tid] + bt[tid]) * mask;
    y[(size_t)row * Dd + tid + 256] = (d1 * inv * g[tid + 256] + bt[tid + 256]) * mask;
}

// ---------------------------------------------------------------------------
// Tiled fp32 GEMM: C[m,n] = act((sum_k A[m,k] W[k,n] + bias[n]) * alpha) (+resid)
// BM=BN=64, BK=16, 256 threads, 4x4 per thread. M,N mult of 64; Kd mult of 16.
// ---------------------------------------------------------------------------
__global__ __launch_bounds__(256) void gemm_kernel(
    const float* __restrict__ A, const float* __restrict__ W,
    const float* __restrict__ bias, const float* __restrict__ resid,
    float* __restrict__ C, int M, int N, int Kd, float alpha, int act)
{
    const int BK = 16, PADW = 68;  // stride 68 keeps float4 alignment + bank spread
    __shared__ float As[BK][PADW];
    __shared__ float Ws[BK][PADW];
    const int tid = threadIdx.x;
    const int bn = blockIdx.x * 64, bm = blockIdx.y * 64;
    const int tx = tid & 15, ty = tid >> 4;
    const int am = tid >> 2, ak = (tid & 3) * 4;    // A-tile load coords
    const int wk = tid >> 4, wn = (tid & 15) * 4;   // W-tile load coords
    float acc[4][4] = {};

    for (int k0 = 0; k0 < Kd; k0 += BK) {
        float4 av = *(const float4*)&A[(size_t)(bm + am) * Kd + k0 + ak];
        float4 wv = *(const float4*)&W[(size_t)(k0 + wk) * N + bn + wn];
        As[ak + 0][am] = av.x; As[ak + 1][am] = av.y;
        As[ak + 2][am] = av.z; As[ak + 3][am] = av.w;
        *(float4*)&Ws[wk][wn] = wv;
        __syncthreads();
#pragma unroll
        for (int kk = 0; kk < BK; ++kk) {
            float4 a4 = *(const float4*)&As[kk][ty * 4];
            float4 w4 = *(const float4*)&Ws[kk][tx * 4];
            float ar[4] = {a4.x, a4.y, a4.z, a4.w};
            float wr[4] = {w4.x, w4.y, w4.z, w4.w};
#pragma unroll
            for (int r = 0; r < 4; ++r)
#pragma unroll
                for (int c = 0; c < 4; ++c) acc[r][c] += ar[r] * wr[c];
        }
        __syncthreads();
    }

    float4 b4 = *(const float4*)&bias[bn + tx * 4];
    float bb[4] = {b4.x, b4.y, b4.z, b4.w};
#pragma unroll
    for (int r = 0; r < 4; ++r) {
        size_t mrow = (size_t)(bm + ty * 4 + r) * N + bn + tx * 4;
        float o[4];
#pragma unroll
        for (int c = 0; c < 4; ++c) {
            float v = (acc[r][c] + bb[c]) * alpha;
            if (act) v = gelu_f(v);
            o[c] = v;
        }
        if (resid) {
            float4 r4 = *(const float4*)&resid[mrow];
            o[0] += r4.x; o[1] += r4.y; o[2] += r4.z; o[3] += r4.w;
        }
        float4 o4 = {o[0], o[1], o[2], o[3]};
        *(float4*)&C[mrow] = o4;
    }
}

// ---------------------------------------------------------------------------
// Fused attention: s = q.k^T + bias (s written back in place -> next layer's
// bias), softmax over j, then o[b,i,h,:] = sum_j p_j * v[b,j,h,:].
// Block = one (b,h,i): 256 threads = 256 j. No attn-prob buffer.
// ---------------------------------------------------------------------------
__global__ __launch_bounds__(256) void attn_fused_kernel(
    const float* __restrict__ q, const float* __restrict__ k,
    const float* __restrict__ v, float* __restrict__ bias_io,
    float* __restrict__ o)
{
    const int i = blockIdx.x, h = blockIdx.y, b = blockIdx.z;
    const int tid = threadIdx.x;
    __shared__ float q_s[DHh];
    __shared__ float sred[4];
    __shared__ float ored[4][DHh];
    if (tid < DHh) q_s[tid] = q[((size_t)b * Ll + i) * Dd + h * DHh + tid];
    __syncthreads();

    const float* kp = &k[((size_t)b * Ll + tid) * Dd + h * DHh];
    float4 ka = *(const float4*)kp;
    float4 kb4 = *(const float4*)(kp + 4);
    float s = q_s[0] * ka.x + q_s[1] * ka.y + q_s[2] * ka.z + q_s[3] * ka.w
            + q_s[4] * kb4.x + q_s[5] * kb4.y + q_s[6] * kb4.z + q_s[7] * kb4.w;
    size_t off = (((size_t)b * Hh + h) * Ll + i) * Ll + tid;
    s += bias_io[off];
    bias_io[off] = s;   // carried bias for next layer (pre-softmax scores)

    // softmax over the 256 j's
    float m = s;
#pragma unroll
    for (int o2 = 32; o2; o2 >>= 1) m = fmaxf(m, __shfl_down(m, o2));
    if ((tid & 63) == 0) sred[tid >> 6] = m;
    __syncthreads();
    m = fmaxf(fmaxf(sred[0], sred[1]), fmaxf(sred[2], sred[3]));
    float e = expf(s - m);
    __syncthreads();
    float t = e;
#pragma unroll
    for (int o2 = 32; o2; o2 >>= 1) t += __shfl_down(t, o2);
    if ((tid & 63) == 0) sred[tid >> 6] = t;
    __syncthreads();
    t = sred[0] + sred[1] + sred[2] + sred[3];
    float p = e / t;

    // PV: thread tid holds p for key row tid; multiply into v row, block-reduce
    const float* vp = &v[((size_t)b * Ll + tid) * Dd + h * DHh];
    float4 va = *(const float4*)vp;
    float4 vb4 = *(const float4*)(vp + 4);
    float pv[DHh] = {p * va.x, p * va.y, p * va.z, p * va.w,
                     p * vb4.x, p * vb4.y, p * vb4.z, p * vb4.w};
#pragma unroll
    for (int e2 = 0; e2 < DHh; ++e2) {
#pragma unroll
        for (int o2 = 32; o2; o2 >>= 1) pv[e2] += __shfl_down(pv[e2], o2);
    }
    if ((tid & 63) == 0) {
#pragma unroll
        for (int e2 = 0; e2 < DHh; ++e2) ored[tid >> 6][e2] = pv[e2];
    }
    __syncthreads();
    if (tid < DHh) {
        float r = ored[0][tid] + ored[1][tid] + ored[2][tid] + ored[3][tid];
        o[((size_t)b * Ll + i) * Dd + h * DHh + tid] = r;
    }
}

// ---------------------------------------------------------------------------
// out[b,d] = mean_i xf[b,i,d]
// ---------------------------------------------------------------------------
__global__ __launch_bounds__(256) void mean_kernel(
    const float* __restrict__ xf, float* __restrict__ out)
{
    const int b = blockIdx.y;
    const int d = blockIdx.x * 64 + (threadIdx.x & 63);
    const int ig = threadIdx.x >> 6;
    float s = 0.f;
    for (int i = ig; i < Ll; i += 4) s += xf[((size_t)b * Ll + i) * Dd + d];
    __shared__ float red[4][64];
    red[ig][threadIdx.x & 63] = s;
    __syncthreads();
    if (threadIdx.x < 64) {
        float tot = red[0][threadIdx.x] + red[1][threadIdx.x]
                  + red[2][threadIdx.x] + red[3][threadIdx.x];
        out[(size_t)b * Dd + blockIdx.x * 64 + threadIdx.x] = tot * (1.0f / Ll);
    }
}

// ---------------------------------------------------------------------------
extern "C" void kernel_launch(void* const* d_in, const int* in_sizes, int n_in,
                              void* d_out, int out_size, void* d_ws, size_t ws_size,
                              hipStream_t stream)
{
    const int*   src_tokens   = (const int*)  d_in[0];
    const float* src_distance = (const float*)d_in[1];
    const int*   src_edge     = (const int*)  d_in[2];
    const float* embed_tokens = (const float*)d_in[3];
    const float* gbf_means    = (const float*)d_in[4];
    const float* gbf_stds     = (const float*)d_in[5];
    const float* gbf_mul      = (const float*)d_in[6];
    const float* gbf_bias     = (const float*)d_in[7];
    const float* proj_w1      = (const float*)d_in[8];
    const float* proj_b1      = (const float*)d_in[9];
    const float* proj_w2      = (const float*)d_in[10];
    const float* proj_b2      = (const float*)d_in[11];
    const float* emb_ln_g     = (const float*)d_in[12];
    const float* emb_ln_b     = (const float*)d_in[13];
    const float* ln1_g        = (const float*)d_in[14];
    const float* ln1_b        = (const float*)d_in[15];
    const float* wq           = (const float*)d_in[16];
    const float* bq           = (const float*)d_in[17];
    const float* wk           = (const float*)d_in[18];
    const float* bk           = (const float*)d_in[19];
    const float* wv           = (const float*)d_in[20];
    const float* bv           = (const float*)d_in[21];
    const float* wo           = (const float*)d_in[22];
    const float* bo           = (const float*)d_in[23];
    const float* ln2_g        = (const float*)d_in[24];
    const float* ln2_b        = (const float*)d_in[25];
    const float* wf1          = (const float*)d_in[26];
    const float* bf1          = (const float*)d_in[27];
    const float* wf2          = (const float*)d_in[28];
    const float* bf2          = (const float*)d_in[29];
    const float* final_ln_g   = (const float*)d_in[30];
    const float* final_ln_b   = (const float*)d_in[31];
    float* out = (float*)d_out;

    // workspace carve-up (floats). Total ~44.0M floats = 176 MB.
    float* ws = (float*)d_ws;
    size_t off = 0;
    const size_t PAIR = (size_t)Bb * Hh * Ll * Ll;   // 33,554,432
    const size_t TOK  = (size_t)Bb * Ll * Dd;        //  1,048,576
    const size_t FFN  = (size_t)Bb * Ll * Ff;        //  4,194,304
    const size_t need = (PAIR + 6 * TOK + FFN) * sizeof(float);
    if (ws_size < need) return;   // diagnosable failure (poisoned out), no fault

    float* bias  = ws + off; off += PAIR;
    float* x     = ws + off; off += TOK;
    float* hbuf  = ws + off; off += TOK;
    float* qb    = ws + off; off += TOK;
    float* kb    = ws + off; off += TOK;
    float* vb    = ws + off; off += TOK;
    float* ob    = ws + off; off += TOK;
    float* tb    = ws + off; off += FFN;

    const float scale = 0.35355339059327373f;  // DH^-0.5

    // pair bias pipeline
    gbf_head_kernel<<<dim3(Ll / JT, Ll, Bb), 256, 0, stream>>>(
        src_distance, src_edge, src_tokens, gbf_means, gbf_stds, gbf_mul,
        gbf_bias, proj_w1, proj_b1, proj_w2, proj_b2, bias);

    // embedding + LN + pad zeroing
    embed_ln_kernel<<<Bb * Ll, 256, 0, stream>>>(
        src_tokens, embed_tokens, emb_ln_g, emb_ln_b, x);

    const int M = Bb * Ll;
    for (int l = 0; l < NLl; ++l) {
        const float* g1 = ln1_g + (size_t)l * Dd;  const float* b1 = ln1_b + (size_t)l * Dd;
        const float* g2 = ln2_g + (size_t)l * Dd;  const float* b2 = ln2_b + (size_t)l * Dd;
        const float* wq_ = wq + (size_t)l * Dd * Dd; const float* bq_ = bq + (size_t)l * Dd;
        const float* wk_ = wk + (size_t)l * Dd * Dd; const float* bk_ = bk + (size_t)l * Dd;
        const float* wv_ = wv + (size_t)l * Dd * Dd; const float* bv_ = bv + (size_t)l * Dd;
        const float* wo_ = wo + (size_t)l * Dd * Dd; const float* bo_ = bo + (size_t)l * Dd;
        const float* wf1_ = wf1 + (size_t)l * Dd * Ff; const float* bf1_ = bf1 + (size_t)l * Ff;
        const float* wf2_ = wf2 + (size_t)l * Ff * Dd; const float* bf2_ = bf2 + (size_t)l * Dd;

        ln_kernel<<<M, 256, 0, stream>>>(x, g1, b1, nullptr, hbuf);
        gemm_kernel<<<dim3(Dd / 64, M / 64), 256, 0, stream>>>(
            hbuf, wq_, bq_, nullptr, qb, M, Dd, Dd, scale, 0);
        gemm_kernel<<<dim3(Dd / 64, M / 64), 256, 0, stream>>>(
            hbuf, wk_, bk_, nullptr, kb, M, Dd, Dd, 1.0f, 0);
        gemm_kernel<<<dim3(Dd / 64, M / 64), 256, 0, stream>>>(
            hbuf, wv_, bv_, nullptr, vb, M, Dd, Dd, 1.0f, 0);
        attn_fused_kernel<<<dim3(Ll, Hh, Bb), 256, 0, stream>>>(
            qb, kb, vb, bias, ob);
        gemm_kernel<<<dim3(Dd / 64, M / 64), 256, 0, stream>>>(
            ob, wo_, bo_, x, x, M, Dd, Dd, 1.0f, 0);
        ln_kernel<<<M, 256, 0, stream>>>(x, g2, b2, nullptr, hbuf);
        gemm_kernel<<<dim3(Ff / 64, M / 64), 256, 0, stream>>>(
            hbuf, wf1_, bf1_, nullptr, tb, M, Ff, Dd, 1.0f, 1);
        gemm_kernel<<<dim3(Dd / 64, M / 64), 256, 0, stream>>>(
            tb, wf2_, bf2_, x, x, M, Dd, Ff, 1.0f, 0);
    }

    // final LN + pad mask -> hbuf, then mean over sequence
    ln_kernel<<<M, 256, 0, stream>>>(x, final_ln_g, final_ln_b, src_tokens, hbuf);
    mean_kernel<<<dim3(Dd / 64, Bb), 256, 0, stream>>>(hbuf, out);
}

// Round 5
// 7182.874 us; speedup vs baseline: 1.6292x; 1.6292x over previous
//
#include <hip/hip_runtime.h>
#include <hip/hip_bf16.h>

// ---------------------------------------------------------------------------
// UniMol encoder forward, round 5 (= round 3 kernel; 2x infra-timeout resubmit).
//   B=8 L=256 D=512 H=64 DH=8 NL=15 K=128 V=128 F=2048, PAD token = 0.
// Changes vs round 2 (last successful run):
//  * All 6 per-layer GEMMs -> MFMA 16x16x32_bf16, 3-term hi/lo split
//    (~2^-18 rel precision, ~fp32-grade). Weights transposed+split into a
//    reused [N][K] bf16 buffer per GEMM; activations pre-split by producers.
//  * LDS staging via global_load_lds(16B) with XOR slot swizzle (src-side).
//  * Attention: 131K blocks -> 16K blocks (8 heads x 32 lanes per block).
//  * ws 172 MB (< 176 MB proven). tb_lo / final-LN alias the dead qkv buf.
// ---------------------------------------------------------------------------

#define Bb 8
#define Ll 256
#define Dd 512
#define Hh 64
#define DHh 8
#define NLl 15
#define Kk 128
#define Ff 2048

typedef unsigned short ushort_t;
typedef __attribute__((ext_vector_type(8))) short short8;
typedef __attribute__((ext_vector_type(4))) float f32x4;

__device__ inline float gelu_f(float v) {
    return 0.5f * v * (1.0f + erff(v * 0.70710678118654752f));
}

__device__ inline void split_bf(float v, ushort_t& hi, ushort_t& lo) {
    __hip_bfloat16 h = __float2bfloat16(v);
    hi = *(ushort_t*)&h;
    float r = v - __bfloat162float(h);
    __hip_bfloat16 l = __float2bfloat16(r);
    lo = *(ushort_t*)&l;
}

__device__ inline void gload_lds16(const ushort_t* g, ushort_t* l) {
    __builtin_amdgcn_global_load_lds(
        (const __attribute__((address_space(1))) unsigned int*)g,
        (__attribute__((address_space(3))) unsigned int*)l, 16, 0, 0);
}

__device__ inline float block_sum256(float v, float* sbuf) {
#pragma unroll
    for (int o2 = 32; o2; o2 >>= 1) v += __shfl_down(v, o2);
    __syncthreads();
    if ((threadIdx.x & 63) == 0) sbuf[threadIdx.x >> 6] = v;
    __syncthreads();
    return sbuf[0] + sbuf[1] + sbuf[2] + sbuf[3];
}

// ---------------------------------------------------------------------------
// Fused GaussianLayer + NonLinearHead + transpose + pad mask (unchanged).
// ---------------------------------------------------------------------------
#define JT 32
__global__ __launch_bounds__(256) void gbf_head_kernel(
    const float* __restrict__ dist, const int* __restrict__ etype,
    const int* __restrict__ tokens,
    const float* __restrict__ means, const float* __restrict__ stds,
    const float* __restrict__ gmul, const float* __restrict__ gbias,
    const float* __restrict__ w1, const float* __restrict__ b1,
    const float* __restrict__ w2, const float* __restrict__ b2,
    float* __restrict__ bias_out)
{
    const int tid = threadIdx.x;
    const int j0 = blockIdx.x * JT;
    const int i  = blockIdx.y;
    const int b  = blockIdx.z;

    __shared__ float mean_s[Kk], istd_s[Kk], coef_s[Kk], b1_s[Kk];
    __shared__ float b2_s[Hh];
    __shared__ float y_s[JT];
    __shared__ int   padj_s[JT];
    __shared__ float gbf_s[JT][Kk];
    __shared__ float u_s[JT][Kk + 1];

    const float SQRT_2PI_F = sqrtf(2.0f * 3.14159f);
    if (tid < Kk) {
        float sd = fabsf(stds[tid]) + 1e-5f;
        float is = 1.0f / sd;
        mean_s[tid] = means[tid];
        istd_s[tid] = is;
        coef_s[tid] = is / SQRT_2PI_F;
        b1_s[tid]   = b1[tid];
    }
    if (tid < Hh) b2_s[tid] = b2[tid];
    if (tid < JT) {
        int j = j0 + tid;
        int t = etype[((size_t)b * Ll + i) * Ll + j];
        y_s[tid]    = gmul[t] * dist[((size_t)b * Ll + i) * Ll + j] + gbias[t];
        padj_s[tid] = (tokens[b * Ll + j] == 0);
    }
    __syncthreads();

    for (int idx = tid; idx < JT * Kk; idx += 256) {
        int jl = idx >> 7, kk = idx & 127;
        float a = (y_s[jl] - mean_s[kk]) * istd_s[kk];
        gbf_s[jl][kk] = coef_s[kk] * expf(-0.5f * a * a);
    }
    __syncthreads();

    {
        const int kp4 = 4 * (tid & 31);
        const int jb  = (tid >> 5) * 4;
        float acc[4][4] = {};
        for (int kk = 0; kk < Kk; ++kk) {
            float4 w = *(const float4*)&w1[kk * Kk + kp4];
            float g[4];
#pragma unroll
            for (int r = 0; r < 4; ++r) g[r] = gbf_s[jb + r][kk];
#pragma unroll
            for (int r = 0; r < 4; ++r) {
                acc[r][0] += g[r] * w.x; acc[r][1] += g[r] * w.y;
                acc[r][2] += g[r] * w.z; acc[r][3] += g[r] * w.w;
            }
        }
#pragma unroll
        for (int r = 0; r < 4; ++r)
#pragma unroll
            for (int c = 0; c < 4; ++c)
                u_s[jb + r][kp4 + c] = gelu_f(acc[r][c] + b1_s[kp4 + c]);
    }
    __syncthreads();

    float (*hb_s)[Hh + 1] = reinterpret_cast<float (*)[Hh + 1]>(&gbf_s[0][0]);
    {
        const int h4  = 4 * (tid >> 4);
        const int jb2 = 2 * (tid & 15);
        float acc[2][4] = {};
        for (int kk = 0; kk < Kk; ++kk) {
            float4 w = *(const float4*)&w2[kk * Hh + h4];
            float u0 = u_s[jb2 + 0][kk];
            float u1 = u_s[jb2 + 1][kk];
            acc[0][0] += u0 * w.x; acc[0][1] += u0 * w.y; acc[0][2] += u0 * w.z; acc[0][3] += u0 * w.w;
            acc[1][0] += u1 * w.x; acc[1][1] += u1 * w.y; acc[1][2] += u1 * w.z; acc[1][3] += u1 * w.w;
        }
        __syncthreads();
#pragma unroll
        for (int r = 0; r < 2; ++r)
#pragma unroll
            for (int c = 0; c < 4; ++c)
                hb_s[jb2 + r][h4 + c] = acc[r][c] + b2_s[h4 + c];
    }
    __syncthreads();

    for (int idx = tid; idx < Hh * JT; idx += 256) {
        int hh = idx >> 5, jl = idx & 31;
        float v = padj_s[jl] ? -INFINITY : hb_s[jl][hh];
        bias_out[(((size_t)b * Hh + hh) * Ll + i) * Ll + j0 + jl] = v;
    }
}

// ---------------------------------------------------------------------------
// Token embedding gather + LayerNorm + pad-row zeroing -> x fp32.
// ---------------------------------------------------------------------------
__global__ __launch_bounds__(256) void embed_ln_kernel(
    const int* __restrict__ tokens, const float* __restrict__ emb,
    const float* __restrict__ g, const float* __restrict__ bt,
    float* __restrict__ x)
{
    int row = blockIdx.x;
    int tid = threadIdx.x;
    int tok = tokens[row];
    const float* e = emb + (size_t)tok * Dd;
    float v0 = e[tid], v1 = e[tid + 256];
    __shared__ float sbuf[4];
    float mean = block_sum256(v0 + v1, sbuf) * (1.0f / Dd);
    float d0 = v0 - mean, d1 = v1 - mean;
    float var = block_sum256(d0 * d0 + d1 * d1, sbuf) * (1.0f / Dd);
    float inv = 1.0f / sqrtf(var + 1e-5f);
    float mask = (tok == 0) ? 0.0f : 1.0f;
    x[(size_t)row * Dd + tid]       = (d0 * inv * g[tid] + bt[tid]) * mask;
    x[(size_t)row * Dd + tid + 256] = (d1 * inv * g[tid + 256] + bt[tid + 256]) * mask;
}

// ---------------------------------------------------------------------------
// LayerNorm. Writes fp32 (yf) and/or bf16 hi/lo split (yhi/ylo). Optional
// pad-row masking via tokens.
// ---------------------------------------------------------------------------
__global__ __launch_bounds__(256) void ln_kernel(
    const float* __restrict__ xin, const float* __restrict__ g,
    const float* __restrict__ bt, const int* __restrict__ tokens,
    float* __restrict__ yf, ushort_t* __restrict__ yhi, ushort_t* __restrict__ ylo)
{
    int row = blockIdx.x;
    int tid = threadIdx.x;
    const float* xr = xin + (size_t)row * Dd;
    float v0 = xr[tid], v1 = xr[tid + 256];
    __shared__ float sbuf[4];
    float mean = block_sum256(v0 + v1, sbuf) * (1.0f / Dd);
    float d0 = v0 - mean, d1 = v1 - mean;
    float var = block_sum256(d0 * d0 + d1 * d1, sbuf) * (1.0f / Dd);
    float inv = 1.0f / sqrtf(var + 1e-5f);
    float mask = 1.0f;
    if (tokens) mask = (tokens[row] == 0) ? 0.0f : 1.0f;
    float y0 = (d0 * inv * g[tid] + bt[tid]) * mask;
    float y1 = (d1 * inv * g[tid + 256] + bt[tid + 256]) * mask;
    size_t o0 = (size_t)row * Dd + tid, o1 = o0 + 256;
    if (yf) { yf[o0] = y0; yf[o1] = y1; }
    if (yhi) {
        ushort_t h, l;
        split_bf(y0, h, l); yhi[o0] = h; ylo[o0] = l;
        split_bf(y1, h, l); yhi[o1] = h; ylo[o1] = l;
    }
}

// ---------------------------------------------------------------------------
// Weight transpose + hi/lo bf16 split: W[K][N] fp32 -> T[N][K] bf16 x2.
// blockIdx.z selects among up to 4 same-shape sources; dest rows offset z*N.
// ---------------------------------------------------------------------------
__global__ __launch_bounds__(256) void transpose_split_kernel(
    const float* s0, const float* s1, const float* s2, const float* s3,
    ushort_t* __restrict__ Th, ushort_t* __restrict__ Tl, int K, int N)
{
    const float* S = (blockIdx.z == 0) ? s0 : (blockIdx.z == 1) ? s1
                    : (blockIdx.z == 2) ? s2 : s3;
    const int n0 = blockIdx.x * 32, k0 = blockIdx.y * 32;
    const int zr = blockIdx.z * N;
    __shared__ float t[32][33];
    int tx = threadIdx.x & 31, ty = threadIdx.x >> 5;
#pragma unroll
    for (int r = 0; r < 4; ++r)
        t[ty + r * 8][tx] = S[(size_t)(k0 + ty + r * 8) * N + n0 + tx];
    __syncthreads();
#pragma unroll
    for (int r = 0; r < 4; ++r) {
        int nn = ty + r * 8;
        float v = t[tx][nn];
        ushort_t h, l;
        split_bf(v, h, l);
        size_t o = (size_t)(zr + n0 + nn) * K + k0 + tx;
        Th[o] = h;
        Tl[o] = l;
    }
}

// ---------------------------------------------------------------------------
// Split-bf16 MFMA GEMM. C[M][N] = epi(sum_k A[m][k]*W[k][n]).
//   A as hi/lo bf16 [M][K]; W as transposed hi/lo bf16 [N][K].
//   3-term: Ah*Wh + Ah*Wl + Al*Wh (fp32 accumulate) ~ 2^-18 rel precision.
// BM=128, BK=32, 256 threads (4 waves, 2x2), wave tile 64 x (BN/2).
// Epilogue: +bias (3-chunk select for fused QKV), alpha on cols<scale_cols,
// optional gelu, optional residual add; out fp32 or split hi/lo.
// ---------------------------------------------------------------------------
template <int BN, bool SPLIT_OUT>
__global__ __launch_bounds__(256) void gemm_split_kernel(
    const ushort_t* __restrict__ Ahi, const ushort_t* __restrict__ Alo,
    const ushort_t* __restrict__ Whi, const ushort_t* __restrict__ Wlo,
    const float* __restrict__ b0, const float* b1, const float* b2,
    const float* __restrict__ resid,
    float* __restrict__ Cf, ushort_t* __restrict__ Chi, ushort_t* __restrict__ Clo,
    int K, int N, float alpha, int scale_cols, int act)
{
    constexpr int BM = 128, BK = 32;
    constexpr int NF = BN / 32;            // n-frags per wave (128->4, 64->2)
    __shared__ ushort_t AsH[BM * BK], AsL[BM * BK];
    __shared__ ushort_t WsH[BN * BK], WsL[BN * BK];

    const int tid = threadIdx.x;
    const int lane = tid & 63, w = tid >> 6;
    const int wm = w >> 1, wn = w & 1;
    const int bm = blockIdx.y * BM, bn = blockIdx.x * BN;
    const int r16 = lane & 15, ksg = lane >> 4;

    // staging coords: 16B unit u -> (row = u>>2, slot = u&3), slot XOR-swizzled
    const int u0 = tid, u1 = tid + 256;
    const int ar0 = u0 >> 2, as0 = (u0 & 3) ^ ((ar0 >> 1) & 3);
    const int ar1 = u1 >> 2, as1 = (u1 & 3) ^ ((ar1 >> 1) & 3);
    const ushort_t* gAh0 = Ahi + (size_t)(bm + ar0) * K + as0 * 8;
    const ushort_t* gAh1 = Ahi + (size_t)(bm + ar1) * K + as1 * 8;
    const ushort_t* gAl0 = Alo + (size_t)(bm + ar0) * K + as0 * 8;
    const ushort_t* gAl1 = Alo + (size_t)(bm + ar1) * K + as1 * 8;
    const ushort_t* gWh0 = Whi + (size_t)(bn + ar0) * K + as0 * 8;
    const ushort_t* gWl0 = Wlo + (size_t)(bn + ar0) * K + as0 * 8;
    const ushort_t* gWh1 = Whi + (size_t)(bn + ar1) * K + as1 * 8;  // BN==128 only
    const ushort_t* gWl1 = Wlo + (size_t)(bn + ar1) * K + as1 * 8;

    // fragment LDS offsets (16B units), constant across K-steps
    int aoff[4], woff[NF];
#pragma unroll
    for (int mb = 0; mb < 4; ++mb) {
        int row = wm * 64 + mb * 16 + r16;
        aoff[mb] = row * 4 + (ksg ^ ((row >> 1) & 3));
    }
#pragma unroll
    for (int nb = 0; nb < NF; ++nb) {
        int row = wn * (BN / 2) + nb * 16 + r16;
        woff[nb] = row * 4 + (ksg ^ ((row >> 1) & 3));
    }

    f32x4 acc[4][NF];
#pragma unroll
    for (int mb = 0; mb < 4; ++mb)
#pragma unroll
        for (int nb = 0; nb < NF; ++nb) acc[mb][nb] = (f32x4){0.f, 0.f, 0.f, 0.f};

    for (int k0 = 0; k0 < K; k0 += BK) {
        __syncthreads();   // all frag reads of prev step done before overwrite
        gload_lds16(gAh0 + k0, AsH + u0 * 8);
        gload_lds16(gAh1 + k0, AsH + u1 * 8);
        gload_lds16(gAl0 + k0, AsL + u0 * 8);
        gload_lds16(gAl1 + k0, AsL + u1 * 8);
        gload_lds16(gWh0 + k0, WsH + u0 * 8);
        gload_lds16(gWl0 + k0, WsL + u0 * 8);
        if (BN == 128) {
            gload_lds16(gWh1 + k0, WsH + u1 * 8);
            gload_lds16(gWl1 + k0, WsL + u1 * 8);
        }
        asm volatile("s_waitcnt vmcnt(0)" ::: "memory");
        __syncthreads();

        short8 ah[4], al[4], bh[NF], bl[NF];
#pragma unroll
        for (int mb = 0; mb < 4; ++mb) {
            ah[mb] = *(const short8*)(AsH + aoff[mb] * 8);
            al[mb] = *(const short8*)(AsL + aoff[mb] * 8);
        }
#pragma unroll
        for (int nb = 0; nb < NF; ++nb) {
            bh[nb] = *(const short8*)(WsH + woff[nb] * 8);
            bl[nb] = *(const short8*)(WsL + woff[nb] * 8);
        }
#pragma unroll
        for (int mb = 0; mb < 4; ++mb)
#pragma unroll
            for (int nb = 0; nb < NF; ++nb) {
                acc[mb][nb] = __builtin_amdgcn_mfma_f32_16x16x32_bf16(ah[mb], bh[nb], acc[mb][nb], 0, 0, 0);
                acc[mb][nb] = __builtin_amdgcn_mfma_f32_16x16x32_bf16(ah[mb], bl[nb], acc[mb][nb], 0, 0, 0);
                acc[mb][nb] = __builtin_amdgcn_mfma_f32_16x16x32_bf16(al[mb], bh[nb], acc[mb][nb], 0, 0, 0);
            }
    }

    const bool fused = (b1 != nullptr);
#pragma unroll
    for (int mb = 0; mb < 4; ++mb)
#pragma unroll
        for (int r = 0; r < 4; ++r) {
            int row = bm + wm * 64 + mb * 16 + ksg * 4 + r;
#pragma unroll
            for (int nb = 0; nb < NF; ++nb) {
                int col = bn + wn * (BN / 2) + nb * 16 + r16;
                float v = acc[mb][nb][r];
                float bv;
                if (fused) {
                    int c9 = col >> 9, ci = col & 511;
                    bv = (c9 == 0 ? b0 : c9 == 1 ? b1 : b2)[ci];
                } else {
                    bv = b0[col];
                }
                v += bv;
                if (col < scale_cols) v *= alpha;
                if (act) v = gelu_f(v);
                size_t oidx = (size_t)row * N + col;
                if (resid) v += resid[oidx];
                if (SPLIT_OUT) {
                    ushort_t h, l;
                    split_bf(v, h, l);
                    Chi[oidx] = h;
                    Clo[oidx] = l;
                } else {
                    Cf[oidx] = v;
                }
            }
        }
}

// ---------------------------------------------------------------------------
// Fused attention: 8 heads per block, 32 lanes per head, 8 j's per lane.
// s = q.k + bias (written back in place -> next layer's bias), softmax,
// o = p.v; output written as bf16 hi/lo split (feeds the Wo GEMM).
// qkv layout: [M][1536] (q | k | v), q pre-scaled by DH^-0.5.
// ---------------------------------------------------------------------------
__global__ __launch_bounds__(256) void attn_fused8_kernel(
    const float* __restrict__ qkv, float* __restrict__ bias_io,
    ushort_t* __restrict__ ohi, ushort_t* __restrict__ olo)
{
    const int hg = blockIdx.x, i = blockIdx.y, b = blockIdx.z;
    const int tid = threadIdx.x;
    const int sub = tid >> 5, l32 = tid & 31;
    const int h = hg * 8 + sub;

    const float* qp = qkv + ((size_t)b * Ll + i) * 1536 + h * 8;
    float4 qa = *(const float4*)qp, qb4 = *(const float4*)(qp + 4);
    const size_t boff = (((size_t)b * Hh + h) * Ll + i) * Ll;

    float s[8];
    float pmax = -3.4e38f;
#pragma unroll
    for (int jj = 0; jj < 8; ++jj) {
        int j = l32 + jj * 32;
        const float* kp = qkv + ((size_t)b * Ll + j) * 1536 + 512 + h * 8;
        float4 ka = *(const float4*)kp, kb4 = *(const float4*)(kp + 4);
        float d = qa.x * ka.x + qa.y * ka.y + qa.z * ka.z + qa.w * ka.w
                + qb4.x * kb4.x + qb4.y * kb4.y + qb4.z * kb4.z + qb4.w * kb4.w;
        float sv = d + bias_io[boff + j];
        bias_io[boff + j] = sv;
        s[jj] = sv;
        pmax = fmaxf(pmax, sv);
    }
#pragma unroll
    for (int m = 16; m; m >>= 1) pmax = fmaxf(pmax, __shfl_xor(pmax, m));
    float esum = 0.f;
#pragma unroll
    for (int jj = 0; jj < 8; ++jj) { s[jj] = expf(s[jj] - pmax); esum += s[jj]; }
#pragma unroll
    for (int m = 16; m; m >>= 1) esum += __shfl_xor(esum, m);
    float inv = 1.f / esum;

    float o[8] = {0.f, 0.f, 0.f, 0.f, 0.f, 0.f, 0.f, 0.f};
#pragma unroll
    for (int jj = 0; jj < 8; ++jj) {
        int j = l32 + jj * 32;
        const float* vp = qkv + ((size_t)b * Ll + j) * 1536 + 1024 + h * 8;
        float4 va = *(const float4*)vp, vb4 = *(const float4*)(vp + 4);
        float pj = s[jj] * inv;
        o[0] += pj * va.x;  o[1] += pj * va.y;  o[2] += pj * va.z;  o[3] += pj * va.w;
        o[4] += pj * vb4.x; o[5] += pj * vb4.y; o[6] += pj * vb4.z; o[7] += pj * vb4.w;
    }
#pragma unroll
    for (int m = 16; m; m >>= 1) {
#pragma unroll
        for (int d = 0; d < 8; ++d) o[d] += __shfl_xor(o[d], m);
    }
    if (l32 < 8) {
        float val = o[0];
#pragma unroll
        for (int d = 1; d < 8; ++d) val = (l32 == d) ? o[d] : val;
        size_t oi = ((size_t)b * Ll + i) * Dd + h * 8 + l32;
        ushort_t hi, lo;
        split_bf(val, hi, lo);
        ohi[oi] = hi;
        olo[oi] = lo;
    }
}

// ---------------------------------------------------------------------------
// out[b,d] = mean_i xf[b,i,d]
// ---------------------------------------------------------------------------
__global__ __launch_bounds__(256) void mean_kernel(
    const float* __restrict__ xf, float* __restrict__ out)
{
    const int b = blockIdx.y;
    const int d = blockIdx.x * 64 + (threadIdx.x & 63);
    const int ig = threadIdx.x >> 6;
    float s = 0.f;
    for (int i = ig; i < Ll; i += 4) s += xf[((size_t)b * Ll + i) * Dd + d];
    __shared__ float red[4][64];
    red[ig][threadIdx.x & 63] = s;
    __syncthreads();
    if (threadIdx.x < 64) {
        float tot = red[0][threadIdx.x] + red[1][threadIdx.x]
                  + red[2][threadIdx.x] + red[3][threadIdx.x];
        out[(size_t)b * Dd + blockIdx.x * 64 + threadIdx.x] = tot * (1.0f / Ll);
    }
}

// ---------------------------------------------------------------------------
extern "C" void kernel_launch(void* const* d_in, const int* in_sizes, int n_in,
                              void* d_out, int out_size, void* d_ws, size_t ws_size,
                              hipStream_t stream)
{
    const int*   src_tokens   = (const int*)  d_in[0];
    const float* src_distance = (const float*)d_in[1];
    const int*   src_edge     = (const int*)  d_in[2];
    const float* embed_tokens = (const float*)d_in[3];
    const float* gbf_means    = (const float*)d_in[4];
    const float* gbf_stds     = (const float*)d_in[5];
    const float* gbf_mul      = (const float*)d_in[6];
    const float* gbf_bias     = (const float*)d_in[7];
    const float* proj_w1      = (const float*)d_in[8];
    const float* proj_b1      = (const float*)d_in[9];
    const float* proj_w2      = (const float*)d_in[10];
    const float* proj_b2      = (const float*)d_in[11];
    const float* emb_ln_g     = (const float*)d_in[12];
    const float* emb_ln_b     = (const float*)d_in[13];
    const float* ln1_g        = (const float*)d_in[14];
    const float* ln1_b        = (const float*)d_in[15];
    const float* wq           = (const float*)d_in[16];
    const float* bq           = (const float*)d_in[17];
    const float* wk           = (const float*)d_in[18];
    const float* bk           = (const float*)d_in[19];
    const float* wv           = (const float*)d_in[20];
    const float* bv           = (const float*)d_in[21];
    const float* wo           = (const float*)d_in[22];
    const float* bo           = (const float*)d_in[23];
    const float* ln2_g        = (const float*)d_in[24];
    const float* ln2_b        = (const float*)d_in[25];
    const float* wf1          = (const float*)d_in[26];
    const float* bf1          = (const float*)d_in[27];
    const float* wf2          = (const float*)d_in[28];
    const float* bf2          = (const float*)d_in[29];
    const float* final_ln_g   = (const float*)d_in[30];
    const float* final_ln_b   = (const float*)d_in[31];
    float* out = (float*)d_out;

    // ---- workspace carve-up (bytes). Total 171,966,464 < 176,160,768 proven.
    char* wsb = (char*)d_ws;
    const size_t SZ_BIAS = 134217728;   // [B][H][L][L] fp32
    const size_t SZ_X    = 4194304;     // [M][512] fp32
    const size_t SZ_QKV  = 12582912;    // [M][1536] fp32 (alias: tb_lo, hbufF)
    const size_t SZ_HS   = 2097152;     // [M][512] bf16 (x4: h_hi,h_lo,ob_hi,ob_lo)
    const size_t SZ_TBH  = 8388608;     // [M][2048] bf16
    const size_t SZ_WT   = 2097152;     // up to [2048][512] bf16 (x2: hi,lo)
    const size_t need = SZ_BIAS + SZ_X + SZ_QKV + 4 * SZ_HS + SZ_TBH + 2 * SZ_WT;
    if (ws_size < need) return;

    size_t off = 0;
    float*    biasP = (float*)(wsb + off);    off += SZ_BIAS;
    float*    x     = (float*)(wsb + off);    off += SZ_X;
    float*    qkvU  = (float*)(wsb + off);    off += SZ_QKV;
    ushort_t* hHi   = (ushort_t*)(wsb + off); off += SZ_HS;
    ushort_t* hLo   = (ushort_t*)(wsb + off); off += SZ_HS;
    ushort_t* obHi  = (ushort_t*)(wsb + off); off += SZ_HS;
    ushort_t* obLo  = (ushort_t*)(wsb + off); off += SZ_HS;
    ushort_t* tbHi  = (ushort_t*)(wsb + off); off += SZ_TBH;
    ushort_t* wTh   = (ushort_t*)(wsb + off); off += SZ_WT;
    ushort_t* wTl   = (ushort_t*)(wsb + off); off += SZ_WT;
    ushort_t* tbLo  = (ushort_t*)qkvU;        // alias (qkv dead after attn)
    float*    hbufF = qkvU;                   // alias (final LN scratch)

    const int M = Bb * Ll;                    // 2048
    const float scale = 0.35355339059327373f; // DH^-0.5

    gbf_head_kernel<<<dim3(Ll / JT, Ll, Bb), 256, 0, stream>>>(
        src_distance, src_edge, src_tokens, gbf_means, gbf_stds, gbf_mul,
        gbf_bias, proj_w1, proj_b1, proj_w2, proj_b2, biasP);

    embed_ln_kernel<<<M, 256, 0, stream>>>(
        src_tokens, embed_tokens, emb_ln_g, emb_ln_b, x);

    for (int l = 0; l < NLl; ++l) {
        const float* g1 = ln1_g + (size_t)l * Dd;  const float* b1 = ln1_b + (size_t)l * Dd;
        const float* g2 = ln2_g + (size_t)l * Dd;  const float* b2 = ln2_b + (size_t)l * Dd;
        const float* wq_ = wq + (size_t)l * Dd * Dd; const float* bq_ = bq + (size_t)l * Dd;
        const float* wk_ = wk + (size_t)l * Dd * Dd; const float* bk_ = bk + (size_t)l * Dd;
        const float* wv_ = wv + (size_t)l * Dd * Dd; const float* bv_ = bv + (size_t)l * Dd;
        const float* wo_ = wo + (size_t)l * Dd * Dd; const float* bo_ = bo + (size_t)l * Dd;
        const float* wf1_ = wf1 + (size_t)l * Dd * Ff; const float* bf1_ = bf1 + (size_t)l * Ff;
        const float* wf2_ = wf2 + (size_t)l * Ff * Dd; const float* bf2_ = bf2 + (size_t)l * Dd;

        // h = LN(x) -> bf16 splits
        ln_kernel<<<M, 256, 0, stream>>>(x, g1, b1, nullptr, nullptr, hHi, hLo);

        // wq,wk,wv,wo -> wT rows [0..1535] + [1536..2047]
        transpose_split_kernel<<<dim3(16, 16, 4), 256, 0, stream>>>(
            wq_, wk_, wv_, wo_, wTh, wTl, 512, 512);

        // QKV fused GEMM: [M][1536], q cols scaled
        gemm_split_kernel<128, false><<<dim3(1536 / 128, M / 128), 256, 0, stream>>>(
            hHi, hLo, wTh, wTl, bq_, bk_, bv_, nullptr,
            qkvU, nullptr, nullptr, 512, 1536, scale, 512, 0);

        attn_fused8_kernel<<<dim3(8, Ll, Bb), 256, 0, stream>>>(
            qkvU, biasP, obHi, obLo);

        // x += ob @ wo
        gemm_split_kernel<64, false><<<dim3(512 / 64, M / 128), 256, 0, stream>>>(
            obHi, obLo, wTh + (size_t)1536 * 512, wTl + (size_t)1536 * 512,
            bo_, nullptr, nullptr, x, x, nullptr, nullptr, 512, 512, 1.0f, 0, 0);

        ln_kernel<<<M, 256, 0, stream>>>(x, g2, b2, nullptr, nullptr, hHi, hLo);

        // wf1 -> wT [2048][512]
        transpose_split_kernel<<<dim3(64, 16, 1), 256, 0, stream>>>(
            wf1_, wf1_, wf1_, wf1_, wTh, wTl, 512, 2048);

        // tb = gelu(h @ wf1 + bf1) -> splits
        gemm_split_kernel<128, true><<<dim3(2048 / 128, M / 128), 256, 0, stream>>>(
            hHi, hLo, wTh, wTl, bf1_, nullptr, nullptr, nullptr,
            nullptr, tbHi, tbLo, 512, 2048, 1.0f, 0, 1);

        // wf2 -> wT [512][2048]
        transpose_split_kernel<<<dim3(16, 64, 1), 256, 0, stream>>>(
            wf2_, wf2_, wf2_, wf2_, wTh, wTl, 2048, 512);

        // x += tb @ wf2
        gemm_split_kernel<64, false><<<dim3(512 / 64, M / 128), 256, 0, stream>>>(
            tbHi, tbLo, wTh, wTl, bf2_, nullptr, nullptr, x,
            x, nullptr, nullptr, 2048, 512, 1.0f, 0, 0);
    }

    ln_kernel<<<M, 256, 0, stream>>>(x, final_ln_g, final_ln_b, src_tokens,
                                     hbufF, nullptr, nullptr);
    mean_kernel<<<dim3(Dd / 64, Bb), 256, 0, stream>>>(hbufF, out);
}